// Round 1
// baseline (334.636 us; speedup 1.0000x reference)
//
#include <hip/hip_runtime.h>
#include <hip/hip_bf16.h>

// GCNConv forward: out = D^-1/2 (A+I) D^-1/2 (x W^T) + b
// N=100000, E=1600000, DIM=128. fp32 in/out, edge_index as int32.
//
// R7: kill the `binned` intermediate (was: 2-pass LDS-atomic binning + bin-local
// counting sort; ~6.4M LDS atomics + 25.7MB scattered-8B intermediate). Direct
// gapped-CSR build:
//   memset(deg) -> hist(global atomics)+Wconv -> csrscan(bin scan, deg->cursor)
//   -> [gemm || placement] -> aggregate (unchanged from R6)

#define DIM 128
#define BINSHIFT 9
#define BINSZ 512            // nodes per bin
#define NB 196               // ceil(100000/512)
#define CAPB 16384           // edges per bin capacity (mean 8192, sd ~90)
#define WSTRIDE 136          // shorts per LDS row in gemm epilogue buffer

typedef __attribute__((ext_vector_type(8))) short short8;
typedef __attribute__((ext_vector_type(4))) float f32x4;
typedef __attribute__((ext_vector_type(4))) unsigned short ushort4v;

__device__ inline unsigned short f2bf(float f) {
    unsigned u = __builtin_bit_cast(unsigned, f);
    return (unsigned short)((u + 0x7FFFu + ((u >> 16) & 1u)) >> 16);
}

// acc[j] += s * bf16_to_f32(v[j]) for 8 bf16 packed in a uint4
__device__ inline void bf8_axpy(uint4 v, float s, float* acc) {
    acc[0] = fmaf(s, __builtin_bit_cast(float, v.x << 16), acc[0]);
    acc[1] = fmaf(s, __builtin_bit_cast(float, v.x & 0xFFFF0000u), acc[1]);
    acc[2] = fmaf(s, __builtin_bit_cast(float, v.y << 16), acc[2]);
    acc[3] = fmaf(s, __builtin_bit_cast(float, v.y & 0xFFFF0000u), acc[3]);
    acc[4] = fmaf(s, __builtin_bit_cast(float, v.z << 16), acc[4]);
    acc[5] = fmaf(s, __builtin_bit_cast(float, v.z & 0xFFFF0000u), acc[5]);
    acc[6] = fmaf(s, __builtin_bit_cast(float, v.w << 16), acc[6]);
    acc[7] = fmaf(s, __builtin_bit_cast(float, v.w & 0xFFFF0000u), acc[7]);
}

// ---- K1: degree histogram (global atomics, int4 reads of dst half) + W->bf16
__global__ __launch_bounds__(256) void hist_wconv(const int* __restrict__ ei, int E,
                                                  int* __restrict__ deg,
                                                  const float* __restrict__ W,
                                                  unsigned short* __restrict__ wbf) {
    int t = threadIdx.x;
    int E4 = E >> 2;
    int nh = (E4 + 255) >> 8;          // hist blocks (must match host launch)
    if ((int)blockIdx.x >= nh) {
        int base = ((int)blockIdx.x - nh) * 1024 + t * 4;  // ushort4v chunks
#pragma unroll
        for (int i = 0; i < 4; ++i) {
            float4 w4 = ((const float4*)W)[base + i];
            ushort4v o; o.x = f2bf(w4.x); o.y = f2bf(w4.y); o.z = f2bf(w4.z); o.w = f2bf(w4.w);
            ((ushort4v*)wbf)[base + i] = o;
        }
        return;
    }
    int i4 = blockIdx.x * 256 + t;
    if (i4 < E4) {
        int4 d = ((const int4*)(ei + E))[i4];
        atomicAdd(&deg[d.x], 1);
        atomicAdd(&deg[d.y], 1);
        atomicAdd(&deg[d.z], 1);
        atomicAdd(&deg[d.w], 1);
    }
    if (blockIdx.x == 0 && t < (E & 3))
        atomicAdd(&deg[ei[E + (E4 << 2) + t]], 1);
}

// ---- K2: per-bin exclusive scan of deg -> rowinfo/dinv; deg becomes cursor --
__global__ __launch_bounds__(256) void csrscan(int* __restrict__ degc,
                                               int2* __restrict__ rowinfo,
                                               float* __restrict__ dinv, int N) {
    __shared__ int ldeg[BINSZ], sa[BINSZ], sb[BINSZ];
    int t = threadIdx.x;
    int b = blockIdx.x;
    for (int i = t; i < BINSZ; i += 256) {
        int n = (b << BINSHIFT) + i;
        ldeg[i] = (n < N) ? degc[n] : 0;
    }
    __syncthreads();
    for (int i = t; i < BINSZ; i += 256) sa[i] = ldeg[i];
    __syncthreads();
    int* src = sa; int* dstp = sb;
    for (int step = 1; step < BINSZ; step <<= 1) {
        for (int i = t; i < BINSZ; i += 256) {
            int v = src[i];
            if (i >= step) v += src[i - step];
            dstp[i] = v;
        }
        __syncthreads();
        int* tmp = src; src = dstp; dstp = tmp;
    }
    // src holds inclusive scan
    for (int i = t; i < BINSZ; i += 256) {
        int n = (b << BINSHIFT) + i;
        if (n < N) {
            int d = ldeg[i];
            int start = b * CAPB + src[i] - d;   // exclusive scan, gapped layout
            rowinfo[n] = make_int2(start, d);
            dinv[n] = rsqrtf((float)(d + 1));    // +1 self loop
            degc[n] = start;                     // re-purpose as placement cursor
        }
    }
}

// ---- K3: MFMA gemm (blocks 0..GB-1) || edge placement (blocks GB..) --------
__global__ __launch_bounds__(256) void gemm_place(const float* __restrict__ x,
                                                  const unsigned short* __restrict__ wbf,
                                                  unsigned short* __restrict__ xlin,
                                                  const int* __restrict__ ei, int E,
                                                  int* __restrict__ cursor,
                                                  int* __restrict__ col, int N) {
    __shared__ unsigned short obuf[4 * 16 * WSTRIDE];   // gemm epilogue (17.4 KB)
    int t = threadIdx.x;
    int GB = (N + 63) >> 6;

    if ((int)blockIdx.x >= GB) {
        // ---- placement role: scatter src ids into dst-sorted gapped CSR
        int pb = (int)blockIdx.x - GB;
        int E4 = E >> 2;
        int i4 = pb * 256 + t;
        if (i4 < E4) {
            int4 s = ((const int4*)ei)[i4];
            int4 d = ((const int4*)(ei + E))[i4];
            col[atomicAdd(&cursor[d.x], 1)] = s.x;
            col[atomicAdd(&cursor[d.y], 1)] = s.y;
            col[atomicAdd(&cursor[d.z], 1)] = s.z;
            col[atomicAdd(&cursor[d.w], 1)] = s.w;
        }
        if (pb == 0 && t < (E & 3)) {
            int i = (E4 << 2) + t;
            col[atomicAdd(&cursor[ei[E + i]], 1)] = ei[i];
        }
        return;
    }

    // ---- GEMM role: wave computes 16 rows x 128 cols; B-frags from bf16 W (L1)
    int wid = t >> 6, lane = t & 63;
    int m = lane & 15, quad = lane >> 4;
    int row_base = blockIdx.x * 64 + wid * 16;

    f32x4 acc[8];
#pragma unroll
    for (int j = 0; j < 8; ++j) acc[j] = (f32x4){0.f, 0.f, 0.f, 0.f};

    int arow = row_base + m;
    if (arow >= N) arow = N - 1;
    const float* xr = x + (size_t)arow * DIM + quad * 8;

#pragma unroll
    for (int kc = 0; kc < 4; ++kc) {
        float4 a0 = *(const float4*)(xr + kc * 32);
        float4 a1 = *(const float4*)(xr + kc * 32 + 4);
        short8 af;
        af[0] = (short)f2bf(a0.x); af[1] = (short)f2bf(a0.y);
        af[2] = (short)f2bf(a0.z); af[3] = (short)f2bf(a0.w);
        af[4] = (short)f2bf(a1.x); af[5] = (short)f2bf(a1.y);
        af[6] = (short)f2bf(a1.z); af[7] = (short)f2bf(a1.w);
#pragma unroll
        for (int jt = 0; jt < 8; ++jt) {
            short8 bf = *(const short8*)&wbf[(jt * 16 + m) * DIM + kc * 32 + quad * 8];
            acc[jt] = __builtin_amdgcn_mfma_f32_16x16x32_bf16(af, bf, acc[jt], 0, 0, 0);
        }
    }

    // epilogue: C layout -> wave-local LDS -> row-major coalesced stores
    unsigned short* ob = &obuf[wid * 16 * WSTRIDE];
#pragma unroll
    for (int jt = 0; jt < 8; ++jt)
#pragma unroll
        for (int r = 0; r < 4; ++r)
            ob[(quad * 4 + r) * WSTRIDE + jt * 16 + m] = f2bf(acc[jt][r]);
#pragma unroll
    for (int it = 0; it < 4; ++it) {
        int idx = it * 64 + lane;
        int r = idx >> 4;
        int cb = idx & 15;
        int grow = row_base + r;
        if (grow < N) {
            short8 v = *(const short8*)&ob[r * WSTRIDE + cb * 8];
            *(short8*)(xlin + (size_t)grow * DIM + cb * 8) = v;
        }
    }
}

// ---- K4: aggregate over gapped CSR: 16 lanes/node, clamped chunks of 4 -----
// (unchanged from R6 for clean attribution)

__global__ __launch_bounds__(256) void aggregate(const unsigned short* __restrict__ xlin,
                                                 const int* __restrict__ col,
                                                 const int2* __restrict__ rowinfo,
                                                 const float* __restrict__ dinv,
                                                 const float* __restrict__ bias,
                                                 float* __restrict__ out, int N) {
    int node = blockIdx.x * 16 + (threadIdx.x >> 4);
    int lane = threadIdx.x & 15;          // owns dims 8*lane .. 8*lane+7
    if (node >= N) return;

    float di = dinv[node];
    int2 ri = rowinfo[node];
    int r0 = ri.x, r1 = ri.x + ri.y;

    const uint4* xl = (const uint4*)xlin;     // 8 bf16 per uint4; 16 per row
    float acc[8] = {};
    bf8_axpy(xl[(size_t)node * 16 + lane], di, acc);   // self loop

    for (int i = r0; i < r1; i += 4) {
        int rem = r1 - i;
        int s0 = col[i];
        int s1 = col[rem > 1 ? i + 1 : i];
        int s2 = col[rem > 2 ? i + 2 : i];
        int s3 = col[rem > 3 ? i + 3 : i];
        float d0 = dinv[s0];
        float d1 = rem > 1 ? dinv[s1] : 0.f;
        float d2 = rem > 2 ? dinv[s2] : 0.f;
        float d3 = rem > 3 ? dinv[s3] : 0.f;
        uint4 v0 = xl[(size_t)s0 * 16 + lane];
        uint4 v1 = xl[(size_t)s1 * 16 + lane];
        uint4 v2 = xl[(size_t)s2 * 16 + lane];
        uint4 v3 = xl[(size_t)s3 * 16 + lane];
        bf8_axpy(v0, d0, acc);
        bf8_axpy(v1, d1, acc);
        bf8_axpy(v2, d2, acc);
        bf8_axpy(v3, d3, acc);
    }

    const float4* b4 = (const float4*)(bias + lane * 8);
    float4 bl = b4[0], bh = b4[1];
    float4 olo = make_float4(di * acc[0] + bl.x, di * acc[1] + bl.y,
                             di * acc[2] + bl.z, di * acc[3] + bl.w);
    float4 ohi = make_float4(di * acc[4] + bh.x, di * acc[5] + bh.y,
                             di * acc[6] + bh.z, di * acc[7] + bh.w);
    float4* op = (float4*)(out + (size_t)node * DIM + lane * 8);
    op[0] = olo;
    op[1] = ohi;
}

// ---- launch ----------------------------------------------------------------

extern "C" void kernel_launch(void* const* d_in, const int* in_sizes, int n_in,
                              void* d_out, int out_size, void* d_ws, size_t ws_size,
                              hipStream_t stream) {
    const float* x    = (const float*)d_in[0];
    const int*   ei   = (const int*)d_in[1];
    const float* W    = (const float*)d_in[2];
    const float* bias = (const float*)d_in[3];
    float* out = (float*)d_out;

    const int N = in_sizes[0] / DIM;      // 100000
    const int E = in_sizes[1] / 2;        // 1600000

    char* ws = (char*)d_ws;
    size_t off = 0;
    auto alloc = [&](size_t bytes) { size_t o = off; off = (off + bytes + 255) & ~(size_t)255; return o; };
    unsigned short* xlin = (unsigned short*)(ws + alloc((size_t)N * DIM * 2));   // 25.6 MB
    int*  col      = (int*)  (ws + alloc((size_t)NB * CAPB * 4));                // 12.85 MB
    int2* rowinfo  = (int2*) (ws + alloc((size_t)N * 8));
    float* dinv    = (float*)(ws + alloc((size_t)N * 4));
    int*  degc     = (int*)  (ws + alloc((size_t)N * 4));                        // deg, then cursor
    unsigned short* wbf = (unsigned short*)(ws + alloc((size_t)DIM * DIM * 2));  // 32 KB

    int E4 = E >> 2;
    int HB = (E4 + 255) >> 8;             // hist / placement blocks
    int GB = (N + 63) >> 6;               // gemm blocks

    hipMemsetAsync(degc, 0, (size_t)N * 4, stream);
    hist_wconv<<<HB + 4, 256, 0, stream>>>(ei, E, degc, W, wbf);
    csrscan<<<NB, 256, 0, stream>>>(degc, rowinfo, dinv, N);
    gemm_place<<<GB + HB, 256, 0, stream>>>(x, wbf, xlin, ei, E, degc, col, N);
    aggregate<<<(N + 15) / 16, 256, 0, stream>>>(xlin, col, rowinfo, dinv, bias, out, N);
}

// Round 2
// 229.530 us; speedup vs baseline: 1.4579x; 1.4579x over previous
//
#include <hip/hip_runtime.h>
#include <hip/hip_bf16.h>

// GCNConv forward: out = D^-1/2 (A+I) D^-1/2 (x W^T) + b
// N=100000, E=1600000, DIM=128. fp32 in/out, edge_index as int32.
//
// R8: R7 falsified (global atomics ~16/us; scattered 4B col stores -> 16x write
// amplification, WRITE_SIZE 129.5MB). Revert to R6's LDS-atomic two-phase
// binning + bin-local counting sort (line-dense writes), but re-schedule:
// GEMM only depends on wbf, so overlap GEMM with the SCATTER (complementary
// pipes: LDS-atomic vs HBM/MFMA), then run csr_build alone (cheap, L2-local).
//   memset(cursors) -> wconv -> [scatter || gemm] -> csr_build -> aggregate

#define DIM 128
#define BINSHIFT 9
#define BINSZ 512            // nodes per bin
#define NB 196               // ceil(100000/512)
#define MAXNB 256
#define CAPB 16384           // edges per bin capacity (mean 8192, sd ~90)
#define WSTRIDE 136          // shorts per LDS row in gemm epilogue buffer
#define SCAT_BLOCKS 256

typedef __attribute__((ext_vector_type(8))) short short8;
typedef __attribute__((ext_vector_type(4))) float f32x4;
typedef __attribute__((ext_vector_type(4))) unsigned short ushort4v;

__device__ inline unsigned short f2bf(float f) {
    unsigned u = __builtin_bit_cast(unsigned, f);
    return (unsigned short)((u + 0x7FFFu + ((u >> 16) & 1u)) >> 16);
}

// acc[j] += s * bf16_to_f32(v[j]) for 8 bf16 packed in a uint4
__device__ inline void bf8_axpy(uint4 v, float s, float* acc) {
    acc[0] = fmaf(s, __builtin_bit_cast(float, v.x << 16), acc[0]);
    acc[1] = fmaf(s, __builtin_bit_cast(float, v.x & 0xFFFF0000u), acc[1]);
    acc[2] = fmaf(s, __builtin_bit_cast(float, v.y << 16), acc[2]);
    acc[3] = fmaf(s, __builtin_bit_cast(float, v.y & 0xFFFF0000u), acc[3]);
    acc[4] = fmaf(s, __builtin_bit_cast(float, v.z << 16), acc[4]);
    acc[5] = fmaf(s, __builtin_bit_cast(float, v.z & 0xFFFF0000u), acc[5]);
    acc[6] = fmaf(s, __builtin_bit_cast(float, v.w << 16), acc[6]);
    acc[7] = fmaf(s, __builtin_bit_cast(float, v.w & 0xFFFF0000u), acc[7]);
}

// ---- K1: W -> bf16 convert (4 blocks, ~3us) --------------------------------
__global__ __launch_bounds__(256) void wconv(const float* __restrict__ W,
                                             unsigned short* __restrict__ wbf) {
    int base = blockIdx.x * 1024 + threadIdx.x * 4;   // ushort4v chunks
#pragma unroll
    for (int i = 0; i < 4; ++i) {
        float4 w4 = ((const float4*)W)[base + i];
        ushort4v o; o.x = f2bf(w4.x); o.y = f2bf(w4.y); o.z = f2bf(w4.z); o.w = f2bf(w4.w);
        ((ushort4v*)wbf)[base + i] = o;
    }
}

// ---- K2: binned scatter (blocks 0..255) || MFMA gemm (blocks 256..) --------
// Scatter: two-pass LDS histogram -> per-(block,bin) contiguous segments in the
// gapped bin layout (line-dense int2 writes, no global per-edge atomics).
// Gemm: wave computes 16 rows x 128 cols from bf16 W (L1-resident).
__global__ __launch_bounds__(256) void scatter_gemm(const int* __restrict__ ei, int E,
                                                    int* __restrict__ binCursor,
                                                    int2* __restrict__ binned,
                                                    const float* __restrict__ x,
                                                    const unsigned short* __restrict__ wbf,
                                                    unsigned short* __restrict__ xlin, int N) {
    __shared__ __align__(16) char smem[4 * 16 * WSTRIDE * 2];   // 17.4 KB, both roles
    int t = threadIdx.x;

    if (blockIdx.x < SCAT_BLOCKS) {
        // ---- scatter role
        int* lh = (int*)smem;          // MAXNB ints
        int* lbase = lh + MAXNB;       // MAXNB ints
        lh[t] = 0;
        __syncthreads();
        int chunk = (E + SCAT_BLOCKS - 1) / SCAT_BLOCKS;
        int base = blockIdx.x * chunk, end = min(E, base + chunk);
        for (int i = base + t; i < end; i += 256)
            atomicAdd(&lh[ei[E + i] >> BINSHIFT], 1);
        __syncthreads();
        if (t < NB) {
            int c = lh[t];
            lbase[t] = c ? atomicAdd(&binCursor[t], c) : 0;
            lh[t] = 0;
        }
        __syncthreads();
        for (int i = base + t; i < end; i += 256) {
            int s = ei[i], d = ei[E + i];
            int b = d >> BINSHIFT;
            int pos = b * CAPB + lbase[b] + atomicAdd(&lh[b], 1);
            binned[pos] = make_int2(s, d);
        }
        return;
    }

    // ---- GEMM role
    unsigned short* obuf = (unsigned short*)smem;
    int wid = t >> 6, lane = t & 63;
    int m = lane & 15, quad = lane >> 4;
    int row_base = (blockIdx.x - SCAT_BLOCKS) * 64 + wid * 16;

    f32x4 acc[8];
#pragma unroll
    for (int j = 0; j < 8; ++j) acc[j] = (f32x4){0.f, 0.f, 0.f, 0.f};

    int arow = row_base + m;
    if (arow >= N) arow = N - 1;
    const float* xr = x + (size_t)arow * DIM + quad * 8;

#pragma unroll
    for (int kc = 0; kc < 4; ++kc) {
        float4 a0 = *(const float4*)(xr + kc * 32);
        float4 a1 = *(const float4*)(xr + kc * 32 + 4);
        short8 af;
        af[0] = (short)f2bf(a0.x); af[1] = (short)f2bf(a0.y);
        af[2] = (short)f2bf(a0.z); af[3] = (short)f2bf(a0.w);
        af[4] = (short)f2bf(a1.x); af[5] = (short)f2bf(a1.y);
        af[6] = (short)f2bf(a1.z); af[7] = (short)f2bf(a1.w);
#pragma unroll
        for (int jt = 0; jt < 8; ++jt) {
            short8 bf = *(const short8*)&wbf[(jt * 16 + m) * DIM + kc * 32 + quad * 8];
            acc[jt] = __builtin_amdgcn_mfma_f32_16x16x32_bf16(af, bf, acc[jt], 0, 0, 0);
        }
    }

    // epilogue: C layout -> wave-local LDS -> row-major coalesced stores
    unsigned short* ob = &obuf[wid * 16 * WSTRIDE];
#pragma unroll
    for (int jt = 0; jt < 8; ++jt)
#pragma unroll
        for (int r = 0; r < 4; ++r)
            ob[(quad * 4 + r) * WSTRIDE + jt * 16 + m] = f2bf(acc[jt][r]);
    __syncthreads();
#pragma unroll
    for (int it = 0; it < 4; ++it) {
        int idx = it * 64 + lane;
        int r = idx >> 4;
        int cb = idx & 15;
        int grow = row_base + r;
        if (grow < N) {
            short8 v = *(const short8*)&ob[r * WSTRIDE + cb * 8];
            *(short8*)(xlin + (size_t)grow * DIM + cb * 8) = v;
        }
    }
}

// ---- K3: bin-local counting sort -> gapped CSR (196 blocks x 512 thr) ------
__global__ __launch_bounds__(512) void csr_build(const int2* __restrict__ binned,
                                                 const int* __restrict__ binCursor,
                                                 int* __restrict__ col,
                                                 int2* __restrict__ rowinfo,
                                                 float* __restrict__ dinv, int N) {
    __shared__ int ldeg[BINSZ], sa[BINSZ], sb[BINSZ], lcur[BINSZ];
    int t = threadIdx.x;          // 0..511, one node per thread
    int b = blockIdx.x;
    int s0 = b * CAPB;
    int s1 = s0 + binCursor[b];

    ldeg[t] = 0; lcur[t] = 0;
    __syncthreads();
    for (int i = s0 + t; i < s1; i += 512)
        atomicAdd(&ldeg[binned[i].y & (BINSZ - 1)], 1);
    __syncthreads();
    sa[t] = ldeg[t];
    __syncthreads();
    int* src = sa; int* dstp = sb;
    for (int step = 1; step < BINSZ; step <<= 1) {
        int v = src[t];
        if (t >= step) v += src[t - step];
        dstp[t] = v;
        __syncthreads();
        int* tmp = src; src = dstp; dstp = tmp;
    }
    // src holds inclusive scan; exclusive start for this node:
    int d = ldeg[t];
    int startoff = src[t] - d;
    int n = (b << BINSHIFT) + t;
    if (n < N) {
        rowinfo[n] = make_int2(s0 + startoff, d);
        dinv[n] = rsqrtf((float)(d + 1));   // +1 self loop
    }
    dstp[t] = startoff;                     // exclusive offsets for placement
    __syncthreads();
    for (int i = s0 + t; i < s1; i += 512) {
        int2 e = binned[i];
        int li = e.y & (BINSZ - 1);
        col[s0 + dstp[li] + atomicAdd(&lcur[li], 1)] = e.x;
    }
}

// ---- K4: aggregate over gapped CSR: 16 lanes/node, clamped chunks of 4 -----
// (unchanged for clean attribution)

__global__ __launch_bounds__(256) void aggregate(const unsigned short* __restrict__ xlin,
                                                 const int* __restrict__ col,
                                                 const int2* __restrict__ rowinfo,
                                                 const float* __restrict__ dinv,
                                                 const float* __restrict__ bias,
                                                 float* __restrict__ out, int N) {
    int node = blockIdx.x * 16 + (threadIdx.x >> 4);
    int lane = threadIdx.x & 15;          // owns dims 8*lane .. 8*lane+7
    if (node >= N) return;

    float di = dinv[node];
    int2 ri = rowinfo[node];
    int r0 = ri.x, r1 = ri.x + ri.y;

    const uint4* xl = (const uint4*)xlin;     // 8 bf16 per uint4; 16 per row
    float acc[8] = {};
    bf8_axpy(xl[(size_t)node * 16 + lane], di, acc);   // self loop

    for (int i = r0; i < r1; i += 4) {
        int rem = r1 - i;
        int s0 = col[i];
        int s1 = col[rem > 1 ? i + 1 : i];
        int s2 = col[rem > 2 ? i + 2 : i];
        int s3 = col[rem > 3 ? i + 3 : i];
        float d0 = dinv[s0];
        float d1 = rem > 1 ? dinv[s1] : 0.f;
        float d2 = rem > 2 ? dinv[s2] : 0.f;
        float d3 = rem > 3 ? dinv[s3] : 0.f;
        uint4 v0 = xl[(size_t)s0 * 16 + lane];
        uint4 v1 = xl[(size_t)s1 * 16 + lane];
        uint4 v2 = xl[(size_t)s2 * 16 + lane];
        uint4 v3 = xl[(size_t)s3 * 16 + lane];
        bf8_axpy(v0, d0, acc);
        bf8_axpy(v1, d1, acc);
        bf8_axpy(v2, d2, acc);
        bf8_axpy(v3, d3, acc);
    }

    const float4* b4 = (const float4*)(bias + lane * 8);
    float4 bl = b4[0], bh = b4[1];
    float4 olo = make_float4(di * acc[0] + bl.x, di * acc[1] + bl.y,
                             di * acc[2] + bl.z, di * acc[3] + bl.w);
    float4 ohi = make_float4(di * acc[4] + bh.x, di * acc[5] + bh.y,
                             di * acc[6] + bh.z, di * acc[7] + bh.w);
    float4* op = (float4*)(out + (size_t)node * DIM + lane * 8);
    op[0] = olo;
    op[1] = ohi;
}

// ---- launch ----------------------------------------------------------------

extern "C" void kernel_launch(void* const* d_in, const int* in_sizes, int n_in,
                              void* d_out, int out_size, void* d_ws, size_t ws_size,
                              hipStream_t stream) {
    const float* x    = (const float*)d_in[0];
    const int*   ei   = (const int*)d_in[1];
    const float* W    = (const float*)d_in[2];
    const float* bias = (const float*)d_in[3];
    float* out = (float*)d_out;

    const int N = in_sizes[0] / DIM;      // 100000
    const int E = in_sizes[1] / 2;        // 1600000

    char* ws = (char*)d_ws;
    size_t off = 0;
    auto alloc = [&](size_t bytes) { size_t o = off; off = (off + bytes + 255) & ~(size_t)255; return o; };
    unsigned short* xlin = (unsigned short*)(ws + alloc((size_t)N * DIM * 2));   // 25.6 MB
    int2* binned   = (int2*) (ws + alloc((size_t)NB * CAPB * 8));                // 25.7 MB
    int*  col      = (int*)  (ws + alloc((size_t)NB * CAPB * 4));                // 12.85 MB
    int2* rowinfo  = (int2*) (ws + alloc((size_t)N * 8));
    float* dinv    = (float*)(ws + alloc((size_t)N * 4));
    int*  binCursor= (int*)  (ws + alloc(MAXNB * 4));
    unsigned short* wbf = (unsigned short*)(ws + alloc((size_t)DIM * DIM * 2));  // 32 KB

    int GB = (N + 63) / 64;               // gemm blocks

    hipMemsetAsync(binCursor, 0, MAXNB * 4, stream);
    wconv<<<4, 256, 0, stream>>>(W, wbf);
    scatter_gemm<<<SCAT_BLOCKS + GB, 256, 0, stream>>>(ei, E, binCursor, binned, x, wbf, xlin, N);
    csr_build<<<NB, 512, 0, stream>>>(binned, binCursor, col, rowinfo, dinv, N);
    aggregate<<<(N + 15) / 16, 256, 0, stream>>>(xlin, col, rowinfo, dinv, bias, out, N);
}